// Round 12
// baseline (209.819 us; speedup 1.0000x reference)
//
#include <hip/hip_runtime.h>
#include <math.h>

// minGRU: hg = x@Whg^T -> gates+scan (fp32, 3-stage) -> out = h@Wout^T
// GEMMs: 256^2 tile, 4-slot LDS ring, 2 sub-phases/slot (16 MFMA each),
// B-frag reuse, shadow af reads, vmcnt once per slot. r3 layout (0 conflicts).
// x[4,4096,1024] f32, W_hg[2048,1024], W_out[1024,1024], out[4,4096,1024] f32

typedef unsigned short ushort_t;
typedef unsigned int uint_t;
typedef __attribute__((ext_vector_type(4))) float f32x4;
typedef __attribute__((ext_vector_type(8))) __bf16 bf16x8;
typedef __attribute__((ext_vector_type(8))) unsigned short u16x8;

constexpr int Bsz  = 4;
constexpr int S    = 4096;
constexpr int Din  = 1024;
constexpr int Dh   = 1024;
constexpr int M    = Bsz * S;      // 16384
constexpr int NCH  = 64;           // scan chunks along S
constexpr int CL   = S / NCH;      // 64

__device__ __forceinline__ unsigned short f2bf(float f) {
    unsigned int u = __float_as_uint(f);
    unsigned int r = (u + 0x7fffu + ((u >> 16) & 1u)) >> 16;   // RTN-even
    return (unsigned short)r;
}
__device__ __forceinline__ float bf2f(unsigned short u) {
    return __uint_as_float(((unsigned int)u) << 16);
}
__device__ __forceinline__ float sigf(float x) {
    x = fminf(fmaxf(x, -30.f), 30.f);
    return 1.0f / (1.0f + __expf(-x));
}
__device__ __forceinline__ void gld_lds16(const ushort_t* g, ushort_t* l) {
    __builtin_amdgcn_global_load_lds(
        (const __attribute__((address_space(1))) void*)g,
        (__attribute__((address_space(3))) void*)l, 16, 0, 0);
}

// one kernel converting all three f32 inputs to bf16
__global__ __launch_bounds__(256) void cvt_all(
    const float* __restrict__ x, const float* __restrict__ whg,
    const float* __restrict__ wout,
    ushort_t* __restrict__ xb, ushort_t* __restrict__ whgb,
    ushort_t* __restrict__ woutb)
{
    constexpr int NX = M * Din / 8;          // 2097152
    constexpr int NW = 2048 * 1024 / 8;      // 262144
    const int i = blockIdx.x * 256 + threadIdx.x;
    const float* src; ushort_t* dst; int k;
    if (i < NX)            { src = x;    dst = xb;    k = i; }
    else if (i < NX + NW)  { src = whg;  dst = whgb;  k = i - NX; }
    else                   { src = wout; dst = woutb; k = i - NX - NW; }
    const float4 a = ((const float4*)src)[(size_t)k * 2];
    const float4 b = ((const float4*)src)[(size_t)k * 2 + 1];
    u16x8 o;
    o[0] = f2bf(a.x); o[1] = f2bf(a.y); o[2] = f2bf(a.z); o[3] = f2bf(a.w);
    o[4] = f2bf(b.x); o[5] = f2bf(b.y); o[6] = f2bf(b.z); o[7] = f2bf(b.w);
    ((u16x8*)dst)[k] = o;
}

// ===== 256x256 GEMM, 4-slot ring, 2 sub-phases per K=32 slot ===============
// Sub-phase grain (m201): 16 MFMA between 2 barriers; sub0 = 8 ds_reads
// (bfr + af-lo) pre-B1, af-hi (4 reads) issued in MFMA shadow pre-B2;
// sub1 = 0 pre-barrier reads (bfr reused). Stage: A(p+2) in sub0,
// B(p+2) in sub1. vmcnt only in sub1 pre-B1.
// Per-wave load FIFO (2 loads/stage): post-vmcnt(4) at sub1(p):
//   outstanding = [A(p+2), B(p+2)]; slot p+1 landed. Prologue vmcnt(4)
//   lands slot 0. Tail: p=P-2 -> vmcnt(0); p=P-1 -> none.
// WAR: stage(p+2) targets slot (p-2)&3, last read >=3 barriers earlier.
template<bool OUT_BF16>
__global__ __launch_bounds__(512, 2) void gemm8p(
    const ushort_t* __restrict__ A, int lda,
    const ushort_t* __restrict__ B, int ldb,
    void* __restrict__ Cout, int ldc, int K, int nbx_log2)
{
    __shared__ ushort_t lds[4][2][8192];   // [slot][A=0/B=1][256*32] = 128 KiB

    const int P = K >> 5;                  // slots (K=1024 -> 32)

    // XCD-bijective block swizzle (gridDim.x % 8 == 0)
    const int nwg = gridDim.x;
    const int cpx = nwg >> 3;
    const int bid = blockIdx.x;
    const int swz = (bid & 7) * cpx + (bid >> 3);
    const int bx  = swz & ((1 << nbx_log2) - 1);
    const int by  = swz >> nbx_log2;
    const int bm0 = by * 256;
    const int bn0 = bx * 256;

    const int t  = threadIdx.x;
    const int w  = t >> 6;           // wave 0..7
    const int l  = t & 63;
    const int wr = w >> 2;           // 0..1 -> 128 rows
    const int wc = w & 3;            // 0..3 -> 64 cols

    // fragment read offsets (elements), swizzle folded in (r3, 0 conflicts)
    const int fr = l & 15;
    const int kg = l >> 4;
    const int qp = kg ^ (((fr >> 3) & 1) << 1);
    const int a_base = wr * 4096 + fr * 32 + qp * 8;   // + i*512
    const int b_base = wc * 2048 + fr * 32 + qp * 8;   // + j*512

    // staging: lane -> (subtile row, quarter); pre-swizzled global source
    const int rs = l >> 2;
    const int lq = (l & 3) ^ (((rs >> 3) & 1) << 1);
    const ushort_t* gA0 = A + (size_t)(bm0 + w * 16 + rs) * lda + lq * 8;
    const ushort_t* gA1 = gA0 + (size_t)128 * lda;
    const ushort_t* gB0 = B + (size_t)(bn0 + w * 16 + rs) * ldb + lq * 8;
    const ushort_t* gB1 = gB0 + (size_t)128 * ldb;

    f32x4 acc[8][4];
    #pragma unroll
    for (int i = 0; i < 8; ++i)
        #pragma unroll
        for (int j = 0; j < 4; ++j)
            acc[i][j] = (f32x4){0.f, 0.f, 0.f, 0.f};

    auto stageA = [&](int p) {
        const int s2 = p & 3;
        const int ko = p * 32;
        gld_lds16(gA0 + ko, &lds[s2][0][w * 512]);
        gld_lds16(gA1 + ko, &lds[s2][0][w * 512 + 4096]);
    };
    auto stageB = [&](int p) {
        const int s2 = p & 3;
        const int ko = p * 32;
        gld_lds16(gB0 + ko, &lds[s2][1][w * 512]);
        gld_lds16(gB1 + ko, &lds[s2][1][w * 512 + 4096]);
    };

    // prologue: slots 0 and 1 (A0,B0,A1,B1 in FIFO order)
    stageA(0); stageB(0); stageA(1); stageB(1);
    asm volatile("s_waitcnt vmcnt(4)" ::: "memory");   // slot 0 landed
    __builtin_amdgcn_s_barrier();
    __builtin_amdgcn_sched_barrier(0);

    #pragma unroll 1
    for (int p = 0; p < P; ++p) {
        const int s = p & 3;
        const ushort_t* la = &lds[s][0][0];
        const ushort_t* lb = &lds[s][1][0];
        bf16x8 bfr[4], af0[4], af1[4];

        // ---- sub0: 8 reads; stage A(p+2); B1; 16 MFMA; shadow af1; B2 ----
        #pragma unroll
        for (int j = 0; j < 4; ++j)
            bfr[j] = *reinterpret_cast<const bf16x8*>(&lb[b_base + j * 512]);
        #pragma unroll
        for (int i = 0; i < 4; ++i)
            af0[i] = *reinterpret_cast<const bf16x8*>(&la[a_base + i * 512]);
        if (p + 2 < P) stageA(p + 2);
        __builtin_amdgcn_sched_barrier(0);
        __builtin_amdgcn_s_barrier();                       // B1
        asm volatile("s_waitcnt lgkmcnt(0)" ::: "memory");
        __builtin_amdgcn_sched_barrier(0);
        __builtin_amdgcn_s_setprio(1);
        #pragma unroll
        for (int i = 0; i < 4; ++i)
            #pragma unroll
            for (int j = 0; j < 4; ++j)
                acc[i][j] = __builtin_amdgcn_mfma_f32_16x16x32_bf16(
                    af0[i], bfr[j], acc[i][j], 0, 0, 0);
        __builtin_amdgcn_s_setprio(0);
        __builtin_amdgcn_sched_barrier(0);
        #pragma unroll
        for (int i = 0; i < 4; ++i)                          // shadow reads
            af1[i] = *reinterpret_cast<const bf16x8*>(&la[a_base + (4 + i) * 512]);
        __builtin_amdgcn_sched_barrier(0);
        __builtin_amdgcn_s_barrier();                       // B2
        __builtin_amdgcn_sched_barrier(0);

        // ---- sub1: stage B(p+2); vmcnt; B1; 16 MFMA (bfr reuse); B2 ----
        if (p + 2 < P) stageB(p + 2);
        __builtin_amdgcn_sched_barrier(0);
        if (p + 2 < P)
            asm volatile("s_waitcnt vmcnt(4)" ::: "memory");  // slot p+1 lands
        else if (p + 1 < P)
            asm volatile("s_waitcnt vmcnt(0)" ::: "memory");  // tail drain
        __builtin_amdgcn_s_barrier();                       // B1'
        asm volatile("s_waitcnt lgkmcnt(0)" ::: "memory");
        __builtin_amdgcn_sched_barrier(0);
        __builtin_amdgcn_s_setprio(1);
        #pragma unroll
        for (int i = 0; i < 4; ++i)
            #pragma unroll
            for (int j = 0; j < 4; ++j)
                acc[4 + i][j] = __builtin_amdgcn_mfma_f32_16x16x32_bf16(
                    af1[i], bfr[j], acc[4 + i][j], 0, 0, 0);
        __builtin_amdgcn_s_setprio(0);
        __builtin_amdgcn_sched_barrier(0);
        __builtin_amdgcn_s_barrier();                       // B2'
        __builtin_amdgcn_sched_barrier(0);
    }

    // epilogue: r3 scatter (measured clean WRITE_SIZE)
    // C/D layout: col = lane&15, row = (lane>>4)*4 + reg
    #pragma unroll
    for (int i = 0; i < 8; ++i) {
        #pragma unroll
        for (int j = 0; j < 4; ++j) {
            const int col = bn0 + wc * 64 + j * 16 + fr;
            #pragma unroll
            for (int r = 0; r < 4; ++r) {
                const int row = bm0 + wr * 128 + i * 16 + kg * 4 + r;
                if (OUT_BF16)
                    ((ushort_t*)Cout)[(size_t)row * ldc + col] = f2bf(acc[i][j][r]);
                else
                    ((float*)Cout)[(size_t)row * ldc + col] = acc[i][j][r];
            }
        }
    }
}

// ===== scan, 3 stages, 2 channels/thread (uint loads) ======================

__global__ __launch_bounds__(256) void scan_stage1(
    const ushort_t* __restrict__ hg, float* __restrict__ Abuf,
    float* __restrict__ hlbuf)
{
    const int bid   = blockIdx.x;
    const int half  = bid & 1;
    const int chunk = (bid >> 1) & (NCH - 1);
    const int b     = bid >> 7;
    const int t     = threadIdx.x;
    const int d     = half * 512 + 2 * t;
    const size_t rowbase = (size_t)(b * S + chunk * CL) * 2048 + d;

    float h0 = 0.f, h1 = 0.f, A0 = 1.f, A1 = 1.f;
    #pragma unroll 4
    for (int i = 0; i < CL; ++i) {
        const ushort_t* rp = hg + rowbase + (size_t)i * 2048;
        const uint_t hp = *(const uint_t*)rp;
        const uint_t gp = *(const uint_t*)(rp + 1024);
        const float hid0 = bf2f((ushort_t)hp), hid1 = bf2f((ushort_t)(hp >> 16));
        const float g0 = bf2f((ushort_t)gp),  g1 = bf2f((ushort_t)(gp >> 16));
        const float c0 = sigf(-g0), z0 = 1.f - c0;
        const float c1 = sigf(-g1), z1 = 1.f - c1;
        const float gv0 = (hid0 >= 0.f) ? (hid0 + 0.5f) : sigf(hid0);
        const float gv1 = (hid1 >= 0.f) ? (hid1 + 0.5f) : sigf(hid1);
        h0 = fmaf(c0, h0, z0 * gv0);  A0 *= c0;
        h1 = fmaf(c1, h1, z1 * gv1);  A1 *= c1;
    }
    const size_t pb = (size_t)(b * NCH + chunk) * 1024 + d;
    *(float2*)&Abuf[pb]  = make_float2(A0, A1);
    *(float2*)&hlbuf[pb] = make_float2(h0, h1);
}

__global__ __launch_bounds__(256) void scan_stage2(
    const float* __restrict__ Abuf, const float* __restrict__ hlbuf,
    float* __restrict__ Hs)
{
    const int g = blockIdx.x * 256 + threadIdx.x;   // 0..B*Dh-1
    const int d = g & (Dh - 1);
    const int b = g >> 10;
    float h = 0.0f;
    for (int ch = 0; ch < NCH; ++ch) {
        const size_t o = (size_t)(b * NCH + ch) * Dh + d;
        Hs[o] = h;
        h = fmaf(Abuf[o], h, hlbuf[o]);
    }
}

__global__ __launch_bounds__(256) void scan_stage3(
    const ushort_t* __restrict__ hg, const float* __restrict__ Hs,
    ushort_t* __restrict__ hout)
{
    const int bid   = blockIdx.x;
    const int half  = bid & 1;
    const int chunk = (bid >> 1) & (NCH - 1);
    const int b     = bid >> 7;
    const int t     = threadIdx.x;
    const int d     = half * 512 + 2 * t;
    const size_t rowbase = (size_t)(b * S + chunk * CL) * 2048 + d;
    const size_t hb      = (size_t)(b * S + chunk * CL) * 1024 + d;

    const float2 hs = *(const float2*)&Hs[(size_t)(b * NCH + chunk) * 1024 + d];
    float h0 = hs.x, h1 = hs.y;
    #pragma unroll 4
    for (int i = 0; i < CL; ++i) {
        const ushort_t* rp = hg + rowbase + (size_t)i * 2048;
        const uint_t hp = *(const uint_t*)rp;
        const uint_t gp = *(const uint_t*)(rp + 1024);
        const float hid0 = bf2f((ushort_t)hp), hid1 = bf2f((ushort_t)(hp >> 16));
        const float g0 = bf2f((ushort_t)gp),  g1 = bf2f((ushort_t)(gp >> 16));
        const float c0 = sigf(-g0), z0 = 1.f - c0;
        const float c1 = sigf(-g1), z1 = 1.f - c1;
        const float gv0 = (hid0 >= 0.f) ? (hid0 + 0.5f) : sigf(hid0);
        const float gv1 = (hid1 >= 0.f) ? (hid1 + 0.5f) : sigf(hid1);
        h0 = fmaf(c0, h0, z0 * gv0);
        h1 = fmaf(c1, h1, z1 * gv1);
        const uint_t o = (uint_t)f2bf(h0) | ((uint_t)f2bf(h1) << 16);
        *(uint_t*)(hout + hb + (size_t)i * 1024) = o;
    }
}

extern "C" void kernel_launch(void* const* d_in, const int* in_sizes, int n_in,
                              void* d_out, int out_size, void* d_ws, size_t ws_size,
                              hipStream_t stream)
{
    (void)in_sizes; (void)n_in; (void)out_size; (void)ws_size;
    const float* x    = (const float*)d_in[0];
    const float* Whg  = (const float*)d_in[1];
    const float* Wout = (const float*)d_in[2];
    float* out = (float*)d_out;

    ushort_t* hgbuf = (ushort_t*)d_ws;                  // [M][2048] bf16  67.1 MB
    ushort_t* xb    = hgbuf + (size_t)M * 2048;         // [M][1024] bf16  33.5 MB (x, then h)
    ushort_t* whgb  = xb + (size_t)M * 1024;            // [2048][1024]     4.2 MB
    ushort_t* woutb = whgb + (size_t)2048 * 1024;       // [1024][1024]     2.1 MB
    float*    Abuf  = (float*)(woutb + (size_t)1024 * 1024);   // 1 MB
    float*    hlbuf = Abuf + (size_t)Bsz * NCH * Dh;           // 1 MB
    float*    Hsbuf = hlbuf + (size_t)Bsz * NCH * Dh;          // 1 MB

    const dim3 blk(256);

    // fused conversion: (2097152 + 262144 + 131072)/256 = 9728 blocks
    cvt_all<<<dim3(9728), blk, 0, stream>>>(x, Whg, Wout, xb, whgb, woutb);

    // GEMM1: hg[M][2048] = x @ Whg^T (bf16 out); grid 8x64 = 512
    gemm8p<true><<<dim3(512), dim3(512), 0, stream>>>(
        xb, Din, whgb, Din, hgbuf, 2048, Din, 3);

    scan_stage1<<<dim3(512), blk, 0, stream>>>(hgbuf, Abuf, hlbuf);
    scan_stage2<<<dim3(Bsz * Dh / 256), blk, 0, stream>>>(Abuf, hlbuf, Hsbuf);
    scan_stage3<<<dim3(512), blk, 0, stream>>>(hgbuf, Hsbuf, xb);

    // GEMM2: out[M][1024] = h @ Wout^T (f32 out); grid 4x64 = 256
    gemm8p<false><<<dim3(256), dim3(512), 0, stream>>>(
        xb, Dh, woutb, Din, out, 1024, Dh, 2);
}

// Round 13
// 207.356 us; speedup vs baseline: 1.0119x; 1.0119x over previous
//
#include <hip/hip_runtime.h>
#include <math.h>

// minGRU: hg = x@Whg^T (r3 256^2 1-barrier schedule) -> gates+scan (fp32, 3-stage)
//         -> out = h@Wout^T (128x256 tile, 4 waves, af8xbfr4, 3-slot ring, 2 blocks/CU)
// x[4,4096,1024] f32, W_hg[2048,1024], W_out[1024,1024], out[4,4096,1024] f32

typedef unsigned short ushort_t;
typedef unsigned int uint_t;
typedef __attribute__((ext_vector_type(4))) float f32x4;
typedef __attribute__((ext_vector_type(8))) __bf16 bf16x8;
typedef __attribute__((ext_vector_type(8))) unsigned short u16x8;

constexpr int Bsz  = 4;
constexpr int S    = 4096;
constexpr int Din  = 1024;
constexpr int Dh   = 1024;
constexpr int M    = Bsz * S;      // 16384
constexpr int NCH  = 64;           // scan chunks along S
constexpr int CL   = S / NCH;      // 64

__device__ __forceinline__ unsigned short f2bf(float f) {
    unsigned int u = __float_as_uint(f);
    unsigned int r = (u + 0x7fffu + ((u >> 16) & 1u)) >> 16;   // RTN-even
    return (unsigned short)r;
}
__device__ __forceinline__ float bf2f(unsigned short u) {
    return __uint_as_float(((unsigned int)u) << 16);
}
__device__ __forceinline__ float sigf(float x) {
    x = fminf(fmaxf(x, -30.f), 30.f);
    return 1.0f / (1.0f + __expf(-x));
}
__device__ __forceinline__ void gld_lds16(const ushort_t* g, ushort_t* l) {
    __builtin_amdgcn_global_load_lds(
        (const __attribute__((address_space(1))) void*)g,
        (__attribute__((address_space(3))) void*)l, 16, 0, 0);
}

// one kernel converting all three f32 inputs to bf16
__global__ __launch_bounds__(256) void cvt_all(
    const float* __restrict__ x, const float* __restrict__ whg,
    const float* __restrict__ wout,
    ushort_t* __restrict__ xb, ushort_t* __restrict__ whgb,
    ushort_t* __restrict__ woutb)
{
    constexpr int NX = M * Din / 8;          // 2097152
    constexpr int NW = 2048 * 1024 / 8;      // 262144
    const int i = blockIdx.x * 256 + threadIdx.x;
    const float* src; ushort_t* dst; int k;
    if (i < NX)            { src = x;    dst = xb;    k = i; }
    else if (i < NX + NW)  { src = whg;  dst = whgb;  k = i - NX; }
    else                   { src = wout; dst = woutb; k = i - NX - NW; }
    const float4 a = ((const float4*)src)[(size_t)k * 2];
    const float4 b = ((const float4*)src)[(size_t)k * 2 + 1];
    u16x8 o;
    o[0] = f2bf(a.x); o[1] = f2bf(a.y); o[2] = f2bf(a.z); o[3] = f2bf(a.w);
    o[4] = f2bf(b.x); o[5] = f2bf(b.y); o[6] = f2bf(b.z); o[7] = f2bf(b.w);
    ((u16x8*)dst)[k] = o;
}

// ============ GEMM1: r3-exact 256x256, 4-slot ring, 1 barrier/phase ========
__global__ __launch_bounds__(512, 2) void gemm256(
    const ushort_t* __restrict__ A, int lda,
    const ushort_t* __restrict__ B, int ldb,
    ushort_t* __restrict__ Cout, int ldc, int K, int nbx_log2)
{
    __shared__ ushort_t lds[4][2][8192];   // [slot][A=0/B=1][256*32] = 128 KiB

    const int P = K >> 5;                  // phases (K=1024 -> 32)

    const int nwg = gridDim.x;
    const int cpx = nwg >> 3;
    const int bid = blockIdx.x;
    const int swz = (bid & 7) * cpx + (bid >> 3);
    const int bx  = swz & ((1 << nbx_log2) - 1);
    const int by  = swz >> nbx_log2;
    const int bm0 = by * 256;
    const int bn0 = bx * 256;

    const int t  = threadIdx.x;
    const int w  = t >> 6;
    const int l  = t & 63;
    const int wr = w >> 2;           // 0..1 -> 128 rows
    const int wc = w & 3;            // 0..3 -> 64 cols

    const int fr = l & 15;
    const int kg = l >> 4;
    const int qp = kg ^ (((fr >> 3) & 1) << 1);
    const int a_base = wr * 4096 + fr * 32 + qp * 8;   // + i*512
    const int b_base = wc * 2048 + fr * 32 + qp * 8;   // + j*512

    const int rs = l >> 2;
    const int lq = (l & 3) ^ (((rs >> 3) & 1) << 1);
    const ushort_t* gA0 = A + (size_t)(bm0 + w * 16 + rs) * lda + lq * 8;
    const ushort_t* gA1 = gA0 + (size_t)128 * lda;
    const ushort_t* gB0 = B + (size_t)(bn0 + w * 16 + rs) * ldb + lq * 8;
    const ushort_t* gB1 = gB0 + (size_t)128 * ldb;

    f32x4 acc[8][4];
    #pragma unroll
    for (int i = 0; i < 8; ++i)
        #pragma unroll
        for (int j = 0; j < 4; ++j)
            acc[i][j] = (f32x4){0.f, 0.f, 0.f, 0.f};

    auto stage = [&](int p) {
        const int s2 = p & 3;
        const int ko = p * 32;
        gld_lds16(gA0 + ko, &lds[s2][0][w * 512]);
        gld_lds16(gA1 + ko, &lds[s2][0][w * 512 + 4096]);
        gld_lds16(gB0 + ko, &lds[s2][1][w * 512]);
        gld_lds16(gB1 + ko, &lds[s2][1][w * 512 + 4096]);
    };

    auto phase_body = [&](int p, bool do_stage) {
        __builtin_amdgcn_s_barrier();
        __builtin_amdgcn_sched_barrier(0);
        const int s = p & 3;
        const ushort_t* la = &lds[s][0][0];
        const ushort_t* lb = &lds[s][1][0];
        bf16x8 af[8], bfr[4];
        #pragma unroll
        for (int i = 0; i < 8; ++i)
            af[i] = *reinterpret_cast<const bf16x8*>(&la[a_base + i * 512]);
        #pragma unroll
        for (int j = 0; j < 4; ++j)
            bfr[j] = *reinterpret_cast<const bf16x8*>(&lb[b_base + j * 512]);
        if (do_stage) stage(p + 2);
        __builtin_amdgcn_sched_barrier(0);
        __builtin_amdgcn_s_setprio(1);
        #pragma unroll
        for (int i = 0; i < 8; ++i)
            #pragma unroll
            for (int j = 0; j < 4; ++j)
                acc[i][j] = __builtin_amdgcn_mfma_f32_16x16x32_bf16(
                    af[i], bfr[j], acc[i][j], 0, 0, 0);
        __builtin_amdgcn_s_setprio(0);
        __builtin_amdgcn_sched_barrier(0);
    };

    stage(0);
    stage(1);

    for (int p = 0; p < P - 1; ++p) {
        asm volatile("s_waitcnt vmcnt(4)" ::: "memory");
        phase_body(p, p < P - 2);
    }
    asm volatile("s_waitcnt vmcnt(0)" ::: "memory");
    phase_body(P - 1, false);

    #pragma unroll
    for (int i = 0; i < 8; ++i) {
        #pragma unroll
        for (int j = 0; j < 4; ++j) {
            const int col = bn0 + wc * 64 + j * 16 + fr;
            #pragma unroll
            for (int r = 0; r < 4; ++r) {
                const int row = bm0 + wr * 128 + i * 16 + kg * 4 + r;
                Cout[(size_t)row * ldc + col] = f2bf(acc[i][j][r]);
            }
        }
    }
}

// ===== GEMM2: 128x256 tile, 4 waves, each wave 128x64 out (af8 x bfr4) =====
// 3-slot ring (24 KiB/slot -> 72 KiB, 2 blocks/CU at ~200 VGPR), r3 sync:
// per phase {vmcnt(6); barrier; reads slot p%3; stage(p+2)->(p+2)%3; MFMA}.
// FIFO (6 loads/stage): entering p outstanding = stage(p)+stage(p+1) = 12;
// vmcnt(6) drains stage(p). Tail p=P-1: vmcnt(0). WAR: slot (p+2)%3 =
// (p-1)%3, readers done before barrier(p); stages issue after that barrier.
// A-frag reads are wave-broadcast (same addr all 4 waves, conflict-free);
// B subtiles are read only by the wave that staged them.
__global__ __launch_bounds__(256) void gemm2w4(
    const ushort_t* __restrict__ A, int lda,
    const ushort_t* __restrict__ B, int ldb,
    float* __restrict__ Cout, int ldc, int K, int nbx_log2)
{
    __shared__ ushort_t lds[3][12288];   // slot: A[0:4096], B[4096:12288] (24 KiB)

    const int P = K >> 5;

    const int nwg = gridDim.x;
    const int cpx = nwg >> 3;
    const int bid = blockIdx.x;
    const int swz = (bid & 7) * cpx + (bid >> 3);
    const int bx  = swz & ((1 << nbx_log2) - 1);
    const int by  = swz >> nbx_log2;
    const int bm0 = by * 128;
    const int bn0 = bx * 256;

    const int t = threadIdx.x;
    const int w = t >> 6;            // wave 0..3 -> cols w*64
    const int l = t & 63;

    const int fr = l & 15;
    const int kg = l >> 4;
    const int qp = kg ^ (((fr >> 3) & 1) << 1);
    const int a_base = fr * 32 + qp * 8;                    // + i*512 (i<8)
    const int b_base = 4096 + w * 2048 + fr * 32 + qp * 8;  // + j*512 (j<4)

    // staging: A subtiles 2w,2w+1 (rows 32w..32w+31); B subtiles 4w..4w+3
    // (cols... rows of B = output cols 64w..64w+63). Pre-swizzled source col.
    const int rs = l >> 2;
    const int lq = (l & 3) ^ (((rs >> 3) & 1) << 1);
    const ushort_t* gA0 = A + (size_t)(bm0 + w * 32 + rs) * lda + lq * 8;
    const ushort_t* gA1 = gA0 + (size_t)16 * lda;
    const ushort_t* gB0 = B + (size_t)(bn0 + w * 64 + rs) * ldb + lq * 8;
    const ushort_t* gB1 = gB0 + (size_t)16 * ldb;
    const ushort_t* gB2 = gB0 + (size_t)32 * ldb;
    const ushort_t* gB3 = gB0 + (size_t)48 * ldb;

    f32x4 acc[8][4];
    #pragma unroll
    for (int i = 0; i < 8; ++i)
        #pragma unroll
        for (int j = 0; j < 4; ++j)
            acc[i][j] = (f32x4){0.f, 0.f, 0.f, 0.f};

    auto stage = [&](int p, int s) {     // 6 loads; slot s = p % 3
        ushort_t* base = &lds[s][0];
        const int ko = p * 32;
        gld_lds16(gA0 + ko, base + w * 1024);
        gld_lds16(gA1 + ko, base + w * 1024 + 512);
        gld_lds16(gB0 + ko, base + 4096 + w * 2048);
        gld_lds16(gB1 + ko, base + 4096 + w * 2048 + 512);
        gld_lds16(gB2 + ko, base + 4096 + w * 2048 + 1024);
        gld_lds16(gB3 + ko, base + 4096 + w * 2048 + 1536);
    };

    auto phase_body = [&](int p, int s, int s2, bool do_stage) {
        __builtin_amdgcn_s_barrier();
        __builtin_amdgcn_sched_barrier(0);
        const ushort_t* ls = &lds[s][0];
        bf16x8 af[8], bfr[4];
        #pragma unroll
        for (int i = 0; i < 8; ++i)
            af[i] = *reinterpret_cast<const bf16x8*>(&ls[a_base + i * 512]);
        #pragma unroll
        for (int j = 0; j < 4; ++j)
            bfr[j] = *reinterpret_cast<const bf16x8*>(&ls[b_base + j * 512]);
        if (do_stage) stage(p + 2, s2);
        __builtin_amdgcn_sched_barrier(0);
        __builtin_amdgcn_s_setprio(1);
        #pragma unroll
        for (int i = 0; i < 8; ++i)
            #pragma unroll
            for (int j = 0; j < 4; ++j)
                acc[i][j] = __builtin_amdgcn_mfma_f32_16x16x32_bf16(
                    af[i], bfr[j], acc[i][j], 0, 0, 0);
        __builtin_amdgcn_s_setprio(0);
        __builtin_amdgcn_sched_barrier(0);
    };

    stage(0, 0);
    stage(1, 1);

    int scur = 0, snx2 = 2;
    #pragma unroll 1
    for (int p = 0; p < P - 1; ++p) {
        asm volatile("s_waitcnt vmcnt(6)" ::: "memory");
        phase_body(p, scur, snx2, p < P - 2);
        scur = (scur == 2) ? 0 : scur + 1;
        snx2 = (snx2 == 2) ? 0 : snx2 + 1;
    }
    asm volatile("s_waitcnt vmcnt(0)" ::: "memory");
    phase_body(P - 1, scur, snx2, false);

    // epilogue: scatter f32 (measured clean WRITE_SIZE)
    #pragma unroll
    for (int i = 0; i < 8; ++i) {
        #pragma unroll
        for (int j = 0; j < 4; ++j) {
            const int col = bn0 + w * 64 + j * 16 + fr;
            #pragma unroll
            for (int r = 0; r < 4; ++r) {
                const int row = bm0 + i * 16 + kg * 4 + r;
                Cout[(size_t)row * ldc + col] = acc[i][j][r];
            }
        }
    }
}

// ===== scan, 3 stages, 2 channels/thread (uint loads) ======================

__global__ __launch_bounds__(256) void scan_stage1(
    const ushort_t* __restrict__ hg, float* __restrict__ Abuf,
    float* __restrict__ hlbuf)
{
    const int bid   = blockIdx.x;
    const int half  = bid & 1;
    const int chunk = (bid >> 1) & (NCH - 1);
    const int b     = bid >> 7;
    const int t     = threadIdx.x;
    const int d     = half * 512 + 2 * t;
    const size_t rowbase = (size_t)(b * S + chunk * CL) * 2048 + d;

    float h0 = 0.f, h1 = 0.f, A0 = 1.f, A1 = 1.f;
    #pragma unroll 4
    for (int i = 0; i < CL; ++i) {
        const ushort_t* rp = hg + rowbase + (size_t)i * 2048;
        const uint_t hp = *(const uint_t*)rp;
        const uint_t gp = *(const uint_t*)(rp + 1024);
        const float hid0 = bf2f((ushort_t)hp), hid1 = bf2f((ushort_t)(hp >> 16));
        const float g0 = bf2f((ushort_t)gp),  g1 = bf2f((ushort_t)(gp >> 16));
        const float c0 = sigf(-g0), z0 = 1.f - c0;
        const float c1 = sigf(-g1), z1 = 1.f - c1;
        const float gv0 = (hid0 >= 0.f) ? (hid0 + 0.5f) : sigf(hid0);
        const float gv1 = (hid1 >= 0.f) ? (hid1 + 0.5f) : sigf(hid1);
        h0 = fmaf(c0, h0, z0 * gv0);  A0 *= c0;
        h1 = fmaf(c1, h1, z1 * gv1);  A1 *= c1;
    }
    const size_t pb = (size_t)(b * NCH + chunk) * 1024 + d;
    *(float2*)&Abuf[pb]  = make_float2(A0, A1);
    *(float2*)&hlbuf[pb] = make_float2(h0, h1);
}

__global__ __launch_bounds__(256) void scan_stage2(
    const float* __restrict__ Abuf, const float* __restrict__ hlbuf,
    float* __restrict__ Hs)
{
    const int g = blockIdx.x * 256 + threadIdx.x;   // 0..B*Dh-1
    const int d = g & (Dh - 1);
    const int b = g >> 10;
    float h = 0.0f;
    for (int ch = 0; ch < NCH; ++ch) {
        const size_t o = (size_t)(b * NCH + ch) * Dh + d;
        Hs[o] = h;
        h = fmaf(Abuf[o], h, hlbuf[o]);
    }
}

__global__ __launch_bounds__(256) void scan_stage3(
    const ushort_t* __restrict__ hg, const float* __restrict__ Hs,
    ushort_t* __restrict__ hout)
{
    const int bid   = blockIdx.x;
    const int half  = bid & 1;
    const int chunk = (bid >> 1) & (NCH - 1);
    const int b     = bid >> 7;
    const int t     = threadIdx.x;
    const int d     = half * 512 + 2 * t;
    const size_t rowbase = (size_t)(b * S + chunk * CL) * 2048 + d;
    const size_t hb      = (size_t)(b * S + chunk * CL) * 1024 + d;

    const float2 hs = *(const float2*)&Hs[(size_t)(b * NCH + chunk) * 1024 + d];
    float h0 = hs.x, h1 = hs.y;
    #pragma unroll 4
    for (int i = 0; i < CL; ++i) {
        const ushort_t* rp = hg + rowbase + (size_t)i * 2048;
        const uint_t hp = *(const uint_t*)rp;
        const uint_t gp = *(const uint_t*)(rp + 1024);
        const float hid0 = bf2f((ushort_t)hp), hid1 = bf2f((ushort_t)(hp >> 16));
        const float g0 = bf2f((ushort_t)gp),  g1 = bf2f((ushort_t)(gp >> 16));
        const float c0 = sigf(-g0), z0 = 1.f - c0;
        const float c1 = sigf(-g1), z1 = 1.f - c1;
        const float gv0 = (hid0 >= 0.f) ? (hid0 + 0.5f) : sigf(hid0);
        const float gv1 = (hid1 >= 0.f) ? (hid1 + 0.5f) : sigf(hid1);
        h0 = fmaf(c0, h0, z0 * gv0);
        h1 = fmaf(c1, h1, z1 * gv1);
        const uint_t o = (uint_t)f2bf(h0) | ((uint_t)f2bf(h1) << 16);
        *(uint_t*)(hout + hb + (size_t)i * 1024) = o;
    }
}

extern "C" void kernel_launch(void* const* d_in, const int* in_sizes, int n_in,
                              void* d_out, int out_size, void* d_ws, size_t ws_size,
                              hipStream_t stream)
{
    (void)in_sizes; (void)n_in; (void)out_size; (void)ws_size;
    const float* x    = (const float*)d_in[0];
    const float* Whg  = (const float*)d_in[1];
    const float* Wout = (const float*)d_in[2];
    float* out = (float*)d_out;

    ushort_t* hgbuf = (ushort_t*)d_ws;                  // [M][2048] bf16  67.1 MB
    ushort_t* xb    = hgbuf + (size_t)M * 2048;         // [M][1024] bf16  33.5 MB (x, then h)
    ushort_t* whgb  = xb + (size_t)M * 1024;            // [2048][1024]     4.2 MB
    ushort_t* woutb = whgb + (size_t)2048 * 1024;       // [1024][1024]     2.1 MB
    float*    Abuf  = (float*)(woutb + (size_t)1024 * 1024);   // 1 MB
    float*    hlbuf = Abuf + (size_t)Bsz * NCH * Dh;           // 1 MB
    float*    Hsbuf = hlbuf + (size_t)Bsz * NCH * Dh;          // 1 MB

    const dim3 blk(256);

    // fused conversion: (2097152 + 262144 + 131072)/256 = 9728 blocks
    cvt_all<<<dim3(9728), blk, 0, stream>>>(x, Whg, Wout, xb, whgb, woutb);

    // GEMM1: hg[M][2048] = x @ Whg^T (bf16 out); 256x256 tile, grid 8x64=512
    gemm256<<<dim3(512), dim3(512), 0, stream>>>(
        xb, Din, whgb, Din, hgbuf, 2048, Din, 3);

    scan_stage1<<<dim3(512), blk, 0, stream>>>(hgbuf, Abuf, hlbuf);
    scan_stage2<<<dim3(Bsz * Dh / 256), blk, 0, stream>>>(Abuf, hlbuf, Hsbuf);
    scan_stage3<<<dim3(512), blk, 0, stream>>>(hgbuf, Hsbuf, xb);

    // GEMM2: out[M][1024] = h @ Wout^T (f32 out); 128x256 tile, grid 4x128=512
    gemm2w4<<<dim3(512), blk, 0, stream>>>(
        xb, Dh, woutb, Din, out, 1024, Dh, 2);
}